// Round 13
// baseline (123.698 us; speedup 1.0000x reference)
//
#include <hip/hip_runtime.h>
#include <hip/hip_bf16.h>

#define NB 4
#define NQ 4096
#define CI 256
#define CO 256
#define NS 8
#define HFEAT 128
#define WFEAT 128
#define NPIX (HFEAT * WFEAT)

typedef short bf16x8 __attribute__((ext_vector_type(8)));
typedef float f32x4 __attribute__((ext_vector_type(4)));

__device__ __forceinline__ unsigned short f2b(float x) {
    union { float f; unsigned u; } v; v.f = x;
    unsigned r = v.u + 0x7fff + ((v.u >> 16) & 1);
    return (unsigned short)(r >> 16);
}
__device__ __forceinline__ float b2f(unsigned short x) {
    union { unsigned u; float f; } v; v.u = ((unsigned)x) << 16;
    return v.f;
}
__device__ __forceinline__ void b2f2(unsigned u, float& a, float& b) {
    union { unsigned x; float f; } va, vb;
    va.x = u << 16;
    vb.x = u & 0xffff0000u;
    a = va.f; b = vb.f;
}
// pack 2 fp32 -> dword of 2 bf16 (lo=a, hi=b), RNE. gfx950-verified.
__device__ __forceinline__ unsigned cvtpk(float a, float b) {
    unsigned r;
    asm("v_cvt_pk_bf16_f32 %0, %1, %2" : "=v"(r) : "v"(a), "v"(b));
    return r;
}
__device__ __forceinline__ void gload16(const void* g, void* l) {
    __builtin_amdgcn_global_load_lds((const __attribute__((address_space(1))) void*)g,
                                     (__attribute__((address_space(3))) void*)l, 16, 0, 0);
}

// ---------------------------------------------------------------------------
// Weight prep: Wk, Wv are [o][c] -> bf16 copy. Wq, Wo are [c][o] -> bf16 [o][c].
__global__ __launch_bounds__(256) void k_prep_w(const float* __restrict__ Wk,
                                                const float* __restrict__ Wv,
                                                const float* __restrict__ Wq,
                                                const float* __restrict__ Wo,
                                                unsigned short* __restrict__ out) {
    int mat = blockIdx.y;
    int base = blockIdx.x * 1024 + threadIdx.x * 4;
    const float* src = (mat == 0) ? Wk : (mat == 1) ? Wv : (mat == 2) ? Wq : Wo;
    unsigned short* dst = out + (size_t)mat * 65536;
    if (mat < 2) {
#pragma unroll
        for (int i = 0; i < 4; ++i) dst[base + i] = f2b(src[base + i]);
    } else {
#pragma unroll
        for (int i = 0; i < 4; ++i) {
            int oi = base + i;
            int o = oi >> 8, c = oi & 255;
            dst[oi] = f2b(src[c * 256 + o]);  // transpose
        }
    }
}

// ---------------------------------------------------------------------------
// Fused: loc = tanh(q @ Wl + bl)  AND  qbf = bf16(q). Single read of queries.
__global__ __launch_bounds__(256) void k_qprep(const float* __restrict__ q,
                                               const float* __restrict__ Wl,
                                               const float* __restrict__ bl,
                                               float* __restrict__ loc,
                                               unsigned short* __restrict__ qbf) {
    __shared__ float qs[32][260];
    __shared__ float wlt[16][260];
    int t = threadIdx.x;
    int row0 = blockIdx.x * 32;
    {
        int rr = t >> 6;
        int c4 = (t & 63) * 4;
#pragma unroll
        for (int i = 0; i < 8; ++i) {
            int r = i * 4 + rr;
            *reinterpret_cast<float4*>(&qs[r][c4]) =
                *reinterpret_cast<const float4*>(q + (size_t)(row0 + r) * CI + c4);
        }
    }
    {
        int c = t;
#pragma unroll
        for (int col = 0; col < 16; ++col) wlt[col][c] = Wl[c * 16 + col];
    }
    __syncthreads();
    {
        int rr = t >> 3, cc = (t & 7) * 32;
        unsigned short* dst = qbf + (size_t)(row0 + rr) * CI + cc;
#pragma unroll
        for (int i = 0; i < 4; ++i) {
            uint4 pk4;
            pk4.x = cvtpk(qs[rr][cc + i * 8 + 0], qs[rr][cc + i * 8 + 1]);
            pk4.y = cvtpk(qs[rr][cc + i * 8 + 2], qs[rr][cc + i * 8 + 3]);
            pk4.z = cvtpk(qs[rr][cc + i * 8 + 4], qs[rr][cc + i * 8 + 5]);
            pk4.w = cvtpk(qs[rr][cc + i * 8 + 6], qs[rr][cc + i * 8 + 7]);
            *reinterpret_cast<uint4*>(dst + i * 8) = pk4;
        }
    }
    int r = t & 31;
    int cg = t >> 5;
    float a0 = bl[cg], a1 = bl[cg + 8];
    for (int c4 = 0; c4 < 256; c4 += 4) {
        float4 qv = *reinterpret_cast<const float4*>(&qs[r][c4]);
        float4 w0 = *reinterpret_cast<const float4*>(&wlt[cg][c4]);
        float4 w1 = *reinterpret_cast<const float4*>(&wlt[cg + 8][c4]);
        a0 = fmaf(qv.x, w0.x, a0); a0 = fmaf(qv.y, w0.y, a0);
        a0 = fmaf(qv.z, w0.z, a0); a0 = fmaf(qv.w, w0.w, a0);
        a1 = fmaf(qv.x, w1.x, a1); a1 = fmaf(qv.y, w1.y, a1);
        a1 = fmaf(qv.z, w1.z, a1); a1 = fmaf(qv.w, w1.w, a1);
    }
    loc[(size_t)(row0 + r) * 16 + cg] = tanhf(a0);
    loc[(size_t)(row0 + r) * 16 + cg + 8] = tanhf(a1);
}

// ---------------------------------------------------------------------------
// k_gemm64: skinny-M MFMA GEMM, 64x128 tile -> 512 blocks (2/CU), 12 KB LDS.
template <int OUT_BF16>
__global__ __launch_bounds__(256) void k_gemm64(const unsigned short* __restrict__ A,
                                                const unsigned short* __restrict__ Bt,
                                                const float* __restrict__ bias,
                                                void* __restrict__ outp) {
    __shared__ unsigned short As[64][32];
    __shared__ unsigned short Bs[128][32];
    int t = threadIdx.x;
    int w = t >> 6, l = t & 63;
    int bm = blockIdx.x >> 1, bc = blockIdx.x & 1;
    int m0 = bm * 64, n0 = bc * 128;
    int wr = w & 1, wc = w >> 1;

    f32x4 acc[2][4];
#pragma unroll
    for (int n = 0; n < 4; ++n) {
        float bv = bias[n0 + wc * 64 + n * 16 + (l & 15)];
#pragma unroll
        for (int m = 0; m < 2; ++m) acc[m][n] = f32x4{bv, bv, bv, bv};
    }

    int ar = wr * 32 + (l & 15);
    int br = wc * 64 + (l & 15);
    int kq = (l >> 4) * 8;
    int srow = (l >> 2);
    int scol = (l & 3) * 8;

    for (int kk = 0; kk < 8; ++kk) {
        int k0 = kk * 32;
        gload16(A + (size_t)(m0 + w * 16 + srow) * CI + k0 + scol, &As[w * 16][0]);
#pragma unroll
        for (int j = 0; j < 2; ++j) {
            int row = w * 32 + j * 16 + srow;
            gload16(Bt + (size_t)(n0 + row) * CI + k0 + scol, &Bs[w * 32 + j * 16][0]);
        }
        __syncthreads();
        bf16x8 af[2], bfr[4];
#pragma unroll
        for (int m = 0; m < 2; ++m) af[m] = *reinterpret_cast<const bf16x8*>(&As[ar + m * 16][kq]);
#pragma unroll
        for (int n = 0; n < 4; ++n) bfr[n] = *reinterpret_cast<const bf16x8*>(&Bs[br + n * 16][kq]);
#pragma unroll
        for (int m = 0; m < 2; ++m)
#pragma unroll
            for (int n = 0; n < 4; ++n)
                acc[m][n] = __builtin_amdgcn_mfma_f32_16x16x32_bf16(af[m], bfr[n], acc[m][n], 0, 0, 0);
        __syncthreads();
    }

    int rbase = m0 + wr * 32 + (l >> 4) * 4;
    int cbase = n0 + wc * 64 + (l & 15);
#pragma unroll
    for (int m = 0; m < 2; ++m)
#pragma unroll
        for (int n = 0; n < 4; ++n)
#pragma unroll
            for (int r = 0; r < 4; ++r) {
                size_t row = rbase + m * 16 + r;
                size_t col = cbase + n * 16;
                if (OUT_BF16)
                    ((unsigned short*)outp)[row * CO + col] = f2b(acc[m][n][r]);
                else
                    ((float*)outp)[row * CO + col] = acc[m][n][r];
            }
}

// ---------------------------------------------------------------------------
// k_proj v5.1 — v5 (native gload16 X staging, operand swap) + m173 source
// pre-swizzle killing the 4-way column-read conflict:
//   staging: lane's 16B block xl -> xl ^ (4*s), s = (ldsrow>>3)&1 (LDS stays
//   linear as gload16 requires); read side compensates px ^ ((lg&1)<<4).
//   Bank algebra: lg{0,2} -> banks 0-15, lg{1,3} -> banks 16-31, 2-way = free.
// XCD map: x = 2b + map (kp[b] in L2 of XCD 2b, vp[b] in 2b+1; matches attn).
__global__ __launch_bounds__(512) void k_proj(const float* __restrict__ keys,
                                              const float* __restrict__ values,
                                              const unsigned short* __restrict__ wbuf,
                                              const float* __restrict__ bK,
                                              const float* __restrict__ bV,
                                              unsigned short* __restrict__ kp,
                                              unsigned short* __restrict__ vp) {
    __shared__ unsigned short Ws[256][40];  // 20 KB, pitch 80 B
    __shared__ float Xs[32][128];           // 16 KB, native [c][px], linear

    int bid = blockIdx.x;                    // 1024 blocks
    int xcd = bid & 7;
    int map = xcd & 1;
    int b = xcd >> 1;
    int px0 = (bid >> 3) << 7;

    const float* X = (map ? values : keys) + (size_t)b * (CI * NPIX);
    const unsigned short* W = wbuf + (size_t)map * 65536;
    const float* bias = map ? bV : bK;
    unsigned short* outp = (map ? vp : kp) + (size_t)b * (NPIX * CO);

    int t = threadIdx.x;
    int w = t >> 6, l = t & 63;
    int wp = w & 1;            // px half (64)
    int woq = w >> 1;          // o quarter (64)
    int lm = l & 15, lg = l >> 4;

    f32x4 acc[4][4];
#pragma unroll
    for (int m = 0; m < 4; ++m) {
        int ob = woq * 64 + m * 16 + lg * 4;
        float4 bv = *reinterpret_cast<const float4*>(bias + ob);
#pragma unroll
        for (int n = 0; n < 4; ++n) acc[m][n] = f32x4{bv.x, bv.y, bv.z, bv.w};
    }

    int wrow = t >> 1;         // W row 0..255
    int wh = (t & 1) * 16;     // 16-short half of 32-ch chunk
    int xl = l & 31;
    int xlr = l >> 5;          // row parity within 1KB pair
    int sxor = (lg & 1) << 4;  // read-side px compensation

    for (int cc = 0; cc < 8; ++cc) {
        // X chunk: 2 gload16 per wave, LDS dest linear; global source block
        // index XOR'd by 4*s so column reads land on disjoint bank halves.
#pragma unroll
        for (int j = 0; j < 2; ++j) {
            int row = w * 4 + 2 * j;          // LDS base row (uniform)
            int lr = row + xlr;               // this half-wave's LDS row
            int sw = (lr >> 3) & 1;
            int gpx = 4 * (xl ^ (sw << 2));   // swizzled global px block
            gload16(X + (size_t)(cc * 32 + lr) * NPIX + px0 + gpx, &Xs[row][0]);
        }
        // W chunk: reg -> padded LDS (2x uint4 per thread, full coverage)
        {
            const uint4* s = reinterpret_cast<const uint4*>(W + (size_t)wrow * CI + cc * 32 + wh);
            uint4 a = s[0], bq4 = s[1];
            uint4* d = reinterpret_cast<uint4*>(&Ws[wrow][wh]);
            d[0] = a;
            d[1] = bq4;
        }
        __syncthreads();

        bf16x8 af[4], bfr[4];
#pragma unroll
        for (int m = 0; m < 4; ++m)
            af[m] = *reinterpret_cast<const bf16x8*>(&Ws[woq * 64 + m * 16 + lm][lg * 8]);
#pragma unroll
        for (int n = 0; n < 4; ++n) {
            int px = (wp * 64 + n * 16 + lm) ^ sxor;
            union { uint4 u; bf16x8 h; } pk;
            pk.u.x = cvtpk(Xs[lg * 8 + 0][px], Xs[lg * 8 + 1][px]);
            pk.u.y = cvtpk(Xs[lg * 8 + 2][px], Xs[lg * 8 + 3][px]);
            pk.u.z = cvtpk(Xs[lg * 8 + 4][px], Xs[lg * 8 + 5][px]);
            pk.u.w = cvtpk(Xs[lg * 8 + 6][px], Xs[lg * 8 + 7][px]);
            bfr[n] = pk.h;
        }
#pragma unroll
        for (int m = 0; m < 4; ++m)
#pragma unroll
            for (int n = 0; n < 4; ++n)
                acc[m][n] = __builtin_amdgcn_mfma_f32_16x16x32_bf16(af[m], bfr[n], acc[m][n], 0, 0, 0);
        __syncthreads();
    }

    // epilogue: C[o][px] -> outp[px][o], 8B contiguous per lane
#pragma unroll
    for (int m = 0; m < 4; ++m) {
        int ob = woq * 64 + m * 16 + lg * 4;
#pragma unroll
        for (int n = 0; n < 4; ++n) {
            int px = px0 + wp * 64 + n * 16 + lm;
            uint2 pk;
            pk.x = cvtpk(acc[m][n][0], acc[m][n][1]);
            pk.y = cvtpk(acc[m][n][2], acc[m][n][3]);
            *reinterpret_cast<uint2*>(outp + (size_t)px * CO + ob) = pk;
        }
    }
}

// ---------------------------------------------------------------------------
// Deformable sampling + attention v3 (R8-proven): phase-split K/V full prefetch.
__global__ __launch_bounds__(256) void k_attn(const unsigned short* __restrict__ kp,
                                              const unsigned short* __restrict__ vp,
                                              const unsigned short* __restrict__ qh,
                                              const float* __restrict__ loc,
                                              unsigned short* __restrict__ aout) {
    int t = threadIdx.x;
    int wv = t >> 6, l = t & 63;
    int blk = blockIdx.x;
    int xcd = blk & 7;
    int b = xcd >> 1;
    int idx = ((blk >> 3) << 1) | (xcd & 1);
    int bq = (b << 12) | (idx << 2) | wv;

    float qv[4];
    {
        uint2 qr = *reinterpret_cast<const uint2*>(qh + (size_t)bq * CO + l * 4);
        b2f2(qr.x, qv[0], qv[1]);
        b2f2(qr.y, qv[2], qv[3]);
    }
    const unsigned short* kb = kp + (size_t)b * NPIX * CO + l * 4;
    const unsigned short* vb = vp + (size_t)b * NPIX * CO + l * 4;
    const float* lq = loc + (size_t)bq * (NS * 2);

    int i00[NS];
    float w00[NS], w01[NS], w10[NS], w11[NS];
    unsigned msks = 0;
#pragma unroll
    for (int s = 0; s < NS; ++s) {
        float gx = (lq[2 * s] + 1.f) * (WFEAT * 0.5f) - 0.5f;
        float gy = (lq[2 * s + 1] + 1.f) * (HFEAT * 0.5f) - 0.5f;
        float x0f = floorf(gx), y0f = floorf(gy);
        int x0 = (int)x0f, y0 = (int)y0f;
        float wx1 = gx - x0f, wy1 = gy - y0f;
        float wx0 = 1.f - wx1, wy0 = 1.f - wy1;
        w00[s] = wx0 * wy0; w01[s] = wx1 * wy0;
        w10[s] = wx0 * wy1; w11[s] = wx1 * wy1;
        unsigned xa = (unsigned)x0 < WFEAT, xb = (unsigned)(x0 + 1) < WFEAT;
        unsigned ya = (unsigned)y0 < HFEAT, yb = (unsigned)(y0 + 1) < HFEAT;
        msks |= ((xa & ya) | ((xb & ya) << 1) | ((xa & yb) << 2) | ((xb & yb) << 3)) << (4 * s);
        i00[s] = (y0 * WFEAT + x0) * CO;
    }

    uint2 cr[NS][4];
#pragma unroll
    for (int s = 0; s < NS; ++s) {
        uint2 z = make_uint2(0u, 0u);
        cr[s][0] = z; cr[s][1] = z; cr[s][2] = z; cr[s][3] = z;
        unsigned m4 = msks >> (4 * s);
        if (m4 & 1) cr[s][0] = *(const uint2*)(kb + i00[s]);
        if (m4 & 2) cr[s][1] = *(const uint2*)(kb + i00[s] + CO);
        if (m4 & 4) cr[s][2] = *(const uint2*)(kb + i00[s] + WFEAT * CO);
        if (m4 & 8) cr[s][3] = *(const uint2*)(kb + i00[s] + (WFEAT + 1) * CO);
    }
    float lg[NS];
#pragma unroll
    for (int s = 0; s < NS; ++s) {
        float d[4];
#pragma unroll
        for (int c = 0; c < 4; ++c) {
            float a0, a1, a2, a3;
            b2f2(cr[s][c].x, a0, a1);
            b2f2(cr[s][c].y, a2, a3);
            d[c] = fmaf(qv[0], a0, fmaf(qv[1], a1, fmaf(qv[2], a2, qv[3] * a3)));
        }
        float p = fmaf(d[0], w00[s], fmaf(d[1], w01[s], fmaf(d[2], w10[s], d[3] * w11[s])));
        p += __shfl_xor(p, 1);
        p += __shfl_xor(p, 2);
        p += __shfl_xor(p, 4);
        lg[s] = p * 0.0625f;
    }
    float mx = fmaxf(fmaxf(fmaxf(lg[0], lg[1]), fmaxf(lg[2], lg[3])),
                     fmaxf(fmaxf(lg[4], lg[5]), fmaxf(lg[6], lg[7])));
    float ws[NS];
    float sum = 0.f;
#pragma unroll
    for (int s = 0; s < NS; ++s) { ws[s] = __expf(lg[s] - mx); sum += ws[s]; }
    float inv = 1.f / sum;
#pragma unroll
    for (int s = 0; s < NS; ++s) ws[s] *= inv;

#pragma unroll
    for (int s = 0; s < NS; ++s) {
        uint2 z = make_uint2(0u, 0u);
        cr[s][0] = z; cr[s][1] = z; cr[s][2] = z; cr[s][3] = z;
        unsigned m4 = msks >> (4 * s);
        if (m4 & 1) cr[s][0] = *(const uint2*)(vb + i00[s]);
        if (m4 & 2) cr[s][1] = *(const uint2*)(vb + i00[s] + CO);
        if (m4 & 4) cr[s][2] = *(const uint2*)(vb + i00[s] + WFEAT * CO);
        if (m4 & 8) cr[s][3] = *(const uint2*)(vb + i00[s] + (WFEAT + 1) * CO);
    }
    float o0 = 0.f, o1 = 0.f, o2 = 0.f, o3 = 0.f;
#pragma unroll
    for (int s = 0; s < NS; ++s) {
        float f0 = ws[s] * w00[s], f1 = ws[s] * w01[s];
        float f2 = ws[s] * w10[s], f3 = ws[s] * w11[s];
        float a0, a1, a2, a3;
        b2f2(cr[s][0].x, a0, a1); b2f2(cr[s][0].y, a2, a3);
        o0 = fmaf(f0, a0, o0); o1 = fmaf(f0, a1, o1);
        o2 = fmaf(f0, a2, o2); o3 = fmaf(f0, a3, o3);
        b2f2(cr[s][1].x, a0, a1); b2f2(cr[s][1].y, a2, a3);
        o0 = fmaf(f1, a0, o0); o1 = fmaf(f1, a1, o1);
        o2 = fmaf(f1, a2, o2); o3 = fmaf(f1, a3, o3);
        b2f2(cr[s][2].x, a0, a1); b2f2(cr[s][2].y, a2, a3);
        o0 = fmaf(f2, a0, o0); o1 = fmaf(f2, a1, o1);
        o2 = fmaf(f2, a2, o2); o3 = fmaf(f2, a3, o3);
        b2f2(cr[s][3].x, a0, a1); b2f2(cr[s][3].y, a2, a3);
        o0 = fmaf(f3, a0, o0); o1 = fmaf(f3, a1, o1);
        o2 = fmaf(f3, a2, o2); o3 = fmaf(f3, a3, o3);
    }

    uint2 pk;
    pk.x = cvtpk(o0, o1);
    pk.y = cvtpk(o2, o3);
    *reinterpret_cast<uint2*>(aout + (size_t)bq * CO + l * 4) = pk;
}

// ---------------------------------------------------------------------------
extern "C" void kernel_launch(void* const* d_in, const int* in_sizes, int n_in,
                              void* d_out, int out_size, void* d_ws, size_t ws_size,
                              hipStream_t stream) {
    (void)in_sizes; (void)n_in; (void)out_size; (void)ws_size;
    const float* queries = (const float*)d_in[0];
    const float* keys    = (const float*)d_in[1];
    const float* values  = (const float*)d_in[2];
    const float* W_loc   = (const float*)d_in[3];
    const float* b_loc   = (const float*)d_in[4];
    const float* W_q     = (const float*)d_in[5];
    const float* b_q     = (const float*)d_in[6];
    const float* W_k     = (const float*)d_in[7];
    const float* b_k     = (const float*)d_in[8];
    const float* W_v     = (const float*)d_in[9];
    const float* b_v     = (const float*)d_in[10];
    const float* W_o     = (const float*)d_in[11];
    const float* b_o     = (const float*)d_in[12];
    float* out = (float*)d_out;

    char* ws = (char*)d_ws;
    unsigned short* kp   = (unsigned short*)(ws);                  // 32 MB
    unsigned short* vp   = (unsigned short*)(ws + 33554432);       // 32 MB
    unsigned short* qbf  = (unsigned short*)(ws + 67108864);       // 8 MB
    unsigned short* aout = (unsigned short*)(ws + 67108864);       // reuses qbf (dead by k_attn)
    unsigned short* qh   = (unsigned short*)(ws + 75497472);       // 8 MB
    float* locb          = (float*)(ws + 83886080);                // 1 MB
    unsigned short* wbuf = (unsigned short*)(ws + 84934656);       // 512 KB

    k_prep_w<<<dim3(64, 4), 256, 0, stream>>>(W_k, W_v, W_q, W_o, wbuf);
    k_qprep<<<dim3(512), 256, 0, stream>>>(queries, W_loc, b_loc, locb, qbf);
    k_gemm64<1><<<dim3(512), 256, 0, stream>>>(qbf, wbuf + 131072, b_q, qh);
    k_proj<<<dim3(1024), 512, 0, stream>>>(keys, values, wbuf, b_k, b_v, kp, vp);
    k_attn<<<dim3(NB * NQ / 4), 256, 0, stream>>>(kp, vp, qh, locb, aout);
    k_gemm64<0><<<dim3(512), 256, 0, stream>>>(aout, wbuf + 196608, b_o, out);
}

// Round 14
// 117.906 us; speedup vs baseline: 1.0491x; 1.0491x over previous
//
#include <hip/hip_runtime.h>
#include <hip/hip_bf16.h>

#define NB 4
#define NQ 4096
#define CI 256
#define CO 256
#define NS 8
#define HFEAT 128
#define WFEAT 128
#define NPIX (HFEAT * WFEAT)

typedef short bf16x8 __attribute__((ext_vector_type(8)));
typedef float f32x4 __attribute__((ext_vector_type(4)));

__device__ __forceinline__ unsigned short f2b(float x) {
    union { float f; unsigned u; } v; v.f = x;
    unsigned r = v.u + 0x7fff + ((v.u >> 16) & 1);
    return (unsigned short)(r >> 16);
}
__device__ __forceinline__ float b2f(unsigned short x) {
    union { unsigned u; float f; } v; v.u = ((unsigned)x) << 16;
    return v.f;
}
__device__ __forceinline__ void b2f2(unsigned u, float& a, float& b) {
    union { unsigned x; float f; } va, vb;
    va.x = u << 16;
    vb.x = u & 0xffff0000u;
    a = va.f; b = vb.f;
}
// pack 2 fp32 -> dword of 2 bf16 (lo=a, hi=b), RNE. gfx950-verified.
__device__ __forceinline__ unsigned cvtpk(float a, float b) {
    unsigned r;
    asm("v_cvt_pk_bf16_f32 %0, %1, %2" : "=v"(r) : "v"(a), "v"(b));
    return r;
}
__device__ __forceinline__ void gload16(const void* g, void* l) {
    __builtin_amdgcn_global_load_lds((const __attribute__((address_space(1))) void*)g,
                                     (__attribute__((address_space(3))) void*)l, 16, 0, 0);
}

// ---------------------------------------------------------------------------
// Weight prep: Wk, Wv are [o][c] -> bf16 copy. Wq, Wo are [c][o] -> bf16 [o][c].
__global__ __launch_bounds__(256) void k_prep_w(const float* __restrict__ Wk,
                                                const float* __restrict__ Wv,
                                                const float* __restrict__ Wq,
                                                const float* __restrict__ Wo,
                                                unsigned short* __restrict__ out) {
    int mat = blockIdx.y;
    int base = blockIdx.x * 1024 + threadIdx.x * 4;
    const float* src = (mat == 0) ? Wk : (mat == 1) ? Wv : (mat == 2) ? Wq : Wo;
    unsigned short* dst = out + (size_t)mat * 65536;
    if (mat < 2) {
#pragma unroll
        for (int i = 0; i < 4; ++i) dst[base + i] = f2b(src[base + i]);
    } else {
#pragma unroll
        for (int i = 0; i < 4; ++i) {
            int oi = base + i;
            int o = oi >> 8, c = oi & 255;
            dst[oi] = f2b(src[c * 256 + o]);  // transpose
        }
    }
}

// ---------------------------------------------------------------------------
// Fused: loc = tanh(q @ Wl + bl)  AND  qbf = bf16(q). Single read of queries.
__global__ __launch_bounds__(256) void k_qprep(const float* __restrict__ q,
                                               const float* __restrict__ Wl,
                                               const float* __restrict__ bl,
                                               float* __restrict__ loc,
                                               unsigned short* __restrict__ qbf) {
    __shared__ float qs[32][260];
    __shared__ float wlt[16][260];
    int t = threadIdx.x;
    int row0 = blockIdx.x * 32;
    {
        int rr = t >> 6;
        int c4 = (t & 63) * 4;
#pragma unroll
        for (int i = 0; i < 8; ++i) {
            int r = i * 4 + rr;
            *reinterpret_cast<float4*>(&qs[r][c4]) =
                *reinterpret_cast<const float4*>(q + (size_t)(row0 + r) * CI + c4);
        }
    }
    {
        int c = t;
#pragma unroll
        for (int col = 0; col < 16; ++col) wlt[col][c] = Wl[c * 16 + col];
    }
    __syncthreads();
    // bf16 conversion write: thread covers row t>>3, 32-ch chunk (t&7)*32
    {
        int rr = t >> 3, cc = (t & 7) * 32;
        unsigned short* dst = qbf + (size_t)(row0 + rr) * CI + cc;
#pragma unroll
        for (int i = 0; i < 4; ++i) {
            uint4 pk4;
            pk4.x = cvtpk(qs[rr][cc + i * 8 + 0], qs[rr][cc + i * 8 + 1]);
            pk4.y = cvtpk(qs[rr][cc + i * 8 + 2], qs[rr][cc + i * 8 + 3]);
            pk4.z = cvtpk(qs[rr][cc + i * 8 + 4], qs[rr][cc + i * 8 + 5]);
            pk4.w = cvtpk(qs[rr][cc + i * 8 + 6], qs[rr][cc + i * 8 + 7]);
            *reinterpret_cast<uint4*>(dst + i * 8) = pk4;
        }
    }
    int r = t & 31;
    int cg = t >> 5;
    float a0 = bl[cg], a1 = bl[cg + 8];
    for (int c4 = 0; c4 < 256; c4 += 4) {
        float4 qv = *reinterpret_cast<const float4*>(&qs[r][c4]);
        float4 w0 = *reinterpret_cast<const float4*>(&wlt[cg][c4]);
        float4 w1 = *reinterpret_cast<const float4*>(&wlt[cg + 8][c4]);
        a0 = fmaf(qv.x, w0.x, a0); a0 = fmaf(qv.y, w0.y, a0);
        a0 = fmaf(qv.z, w0.z, a0); a0 = fmaf(qv.w, w0.w, a0);
        a1 = fmaf(qv.x, w1.x, a1); a1 = fmaf(qv.y, w1.y, a1);
        a1 = fmaf(qv.z, w1.z, a1); a1 = fmaf(qv.w, w1.w, a1);
    }
    loc[(size_t)(row0 + r) * 16 + cg] = tanhf(a0);
    loc[(size_t)(row0 + r) * 16 + cg + 8] = tanhf(a1);
}

// ---------------------------------------------------------------------------
// MFMA GEMM (m97 structure): C[M][256] = A[M][256] * Bt[256][256]^T + bias
template <int OUT_BF16>
__global__ __launch_bounds__(256) void k_gemm(const unsigned short* __restrict__ A,
                                              const unsigned short* __restrict__ Bt,
                                              const float* __restrict__ bias,
                                              void* __restrict__ outp) {
    __shared__ unsigned short As[128][32];
    __shared__ unsigned short Bs[128][32];
    int t = threadIdx.x;
    int w = t >> 6, l = t & 63;
    int bm = blockIdx.x >> 1, bc = blockIdx.x & 1;
    int m0 = bm * 128, n0 = bc * 128;
    int wr = w >> 1, wc = w & 1;

    f32x4 acc[4][4];
#pragma unroll
    for (int n = 0; n < 4; ++n) {
        float bv = bias[n0 + wc * 64 + n * 16 + (l & 15)];
#pragma unroll
        for (int m = 0; m < 4; ++m) acc[m][n] = f32x4{bv, bv, bv, bv};
    }

    int ar = wr * 64 + (l & 15);
    int br = wc * 64 + (l & 15);
    int kq = (l >> 4) * 8;
    int srow = (l >> 2);
    int scol = (l & 3) * 8;

    for (int kk = 0; kk < 8; ++kk) {
        int k0 = kk * 32;
#pragma unroll
        for (int j = 0; j < 2; ++j) {
            int row = w * 32 + j * 16 + srow;
            gload16(A + (size_t)(m0 + row) * CI + k0 + scol, &As[w * 32 + j * 16][0]);
            gload16(Bt + (size_t)(n0 + row) * CI + k0 + scol, &Bs[w * 32 + j * 16][0]);
        }
        __syncthreads();
        bf16x8 af[4], bfr[4];
#pragma unroll
        for (int m = 0; m < 4; ++m) af[m] = *reinterpret_cast<const bf16x8*>(&As[ar + m * 16][kq]);
#pragma unroll
        for (int n = 0; n < 4; ++n) bfr[n] = *reinterpret_cast<const bf16x8*>(&Bs[br + n * 16][kq]);
#pragma unroll
        for (int m = 0; m < 4; ++m)
#pragma unroll
            for (int n = 0; n < 4; ++n)
                acc[m][n] = __builtin_amdgcn_mfma_f32_16x16x32_bf16(af[m], bfr[n], acc[m][n], 0, 0, 0);
        __syncthreads();
    }

    int rbase = m0 + wr * 64 + (l >> 4) * 4;
    int cbase = n0 + wc * 64 + (l & 15);
#pragma unroll
    for (int m = 0; m < 4; ++m)
#pragma unroll
        for (int n = 0; n < 4; ++n)
#pragma unroll
            for (int r = 0; r < 4; ++r) {
                size_t row = rbase + m * 16 + r;
                size_t col = cbase + n * 16;
                if (OUT_BF16)
                    ((unsigned short*)outp)[row * CO + col] = f2b(acc[m][n][r]);
                else
                    ((float*)outp)[row * CO + col] = acc[m][n][r];
            }
}

// ---------------------------------------------------------------------------
// Fused 1x1-conv projection (R5/R8-proven, best measured total): float4
// A-loads, XOR-swizzled pair-packed LDS writes, register A-prefetch + dbuf B.
__global__ __launch_bounds__(256) void k_proj(const float* __restrict__ keys,
                                              const float* __restrict__ values,
                                              const unsigned short* __restrict__ wbuf,
                                              const float* __restrict__ bK,
                                              const float* __restrict__ bV,
                                              unsigned short* __restrict__ kp,
                                              unsigned short* __restrict__ vp) {
    __shared__ unsigned short As[128][40];
    __shared__ unsigned short Bs[2][128][32];
    int blk = ((blockIdx.x & 7) << 8) | (blockIdx.x >> 3);  // XCD swizzle (bijective)
    int map = blk >> 10;
    int rem = blk & 1023;
    int b = rem >> 8;
    int rem2 = rem & 255;
    int pix0 = (rem2 >> 1) * 128;
    int o0 = (rem2 & 1) * 128;
    const float* X = (map ? values : keys) + (size_t)b * (CI * NPIX);
    const unsigned short* W = wbuf + (size_t)map * 65536;
    const float* bias = map ? bV : bK;
    unsigned short* outp = (map ? vp : kp) + (size_t)b * (NPIX * CO);

    int t = threadIdx.x;
    int w = t >> 6, l = t & 63;
    int wr = w >> 1, wc = w & 1;

    f32x4 acc[4][4];
#pragma unroll
    for (int n = 0; n < 4; ++n) {
        float bv = bias[o0 + wc * 64 + n * 16 + (l & 15)];
#pragma unroll
        for (int m = 0; m < 4; ++m) acc[m][n] = f32x4{bv, bv, bv, bv};
    }

    int cp0 = t >> 5;
    int pxl = 4 * (t & 31);
    int fx = ((t & 31) ^ ((t & 31) >> 2)) & 3;
    int colA = cp0 ^ (fx << 2);
    int colB = (cp0 + 8) ^ (fx << 2);
    const float* Xp = X + pix0 + pxl;

    int srow = l >> 2, scol = (l & 3) * 8;

    int ar = wr * 64 + (l & 15);
    int br = wc * 64 + (l & 15);
    int g = l >> 4;
    int kq = g * 8;

    float4 fa0, fa1, fa2, fa3;

#define LOADA(kk)                                                         \
    {                                                                     \
        const float* p_ = Xp + (size_t)((kk) * 32 + 2 * cp0) * NPIX;      \
        fa0 = *(const float4*)(p_);                                       \
        fa1 = *(const float4*)(p_ + NPIX);                                \
        fa2 = *(const float4*)(p_ + 16 * NPIX);                           \
        fa3 = *(const float4*)(p_ + 17 * NPIX);                           \
    }
#define WRITEA()                                                          \
    {                                                                     \
        const float* q0_ = (const float*)&fa0;                            \
        const float* q1_ = (const float*)&fa1;                            \
        const float* q2_ = (const float*)&fa2;                            \
        const float* q3_ = (const float*)&fa3;                            \
        _Pragma("unroll")                                                 \
        for (int j = 0; j < 4; ++j) {                                     \
            unsigned d0_ = (unsigned)f2b(q0_[j]) | ((unsigned)f2b(q1_[j]) << 16); \
            unsigned d1_ = (unsigned)f2b(q2_[j]) | ((unsigned)f2b(q3_[j]) << 16); \
            unsigned* rp_ = (unsigned*)&As[pxl + j][0];                   \
            rp_[colA] = d0_;                                              \
            rp_[colB] = d1_;                                              \
        }                                                                 \
    }
#define LOADB(kk, buf)                                                    \
    {                                                                     \
        int k0_ = (kk) * 32;                                              \
        _Pragma("unroll")                                                 \
        for (int j = 0; j < 2; ++j) {                                     \
            int row_ = w * 32 + j * 16;                                   \
            gload16(W + (size_t)(o0 + row_ + srow) * CI + k0_ + scol,     \
                    &Bs[buf][row_][0]);                                   \
        }                                                                 \
    }

    LOADA(0);
    LOADB(0, 0);
    WRITEA();
    __syncthreads();

    for (int kk = 0; kk < 8; ++kk) {
        if (kk < 7) {
            LOADA(kk + 1);
            LOADB(kk + 1, (kk + 1) & 1);
        }
        bf16x8 af[4], bfr[4];
#pragma unroll
        for (int m = 0; m < 4; ++m) {
            int p = ar + m * 16;
            int gm = (g ^ (((p >> 2) ^ (p >> 4)) & 3)) * 8;
            af[m] = *reinterpret_cast<const bf16x8*>(&As[p][gm]);
        }
#pragma unroll
        for (int n = 0; n < 4; ++n)
            bfr[n] = *reinterpret_cast<const bf16x8*>(&Bs[kk & 1][br + n * 16][kq]);
#pragma unroll
        for (int m = 0; m < 4; ++m)
#pragma unroll
            for (int n = 0; n < 4; ++n)
                acc[m][n] = __builtin_amdgcn_mfma_f32_16x16x32_bf16(af[m], bfr[n], acc[m][n], 0, 0, 0);
        __syncthreads();
        if (kk < 7) {
            WRITEA();
            __syncthreads();
        }
    }

    int rbase = wr * 64 + (l >> 4) * 4;
    int cbase = o0 + wc * 64 + (l & 15);
#pragma unroll
    for (int m = 0; m < 4; ++m)
#pragma unroll
        for (int n = 0; n < 4; ++n)
#pragma unroll
            for (int r = 0; r < 4; ++r) {
                size_t row = (size_t)pix0 + rbase + m * 16 + r;
                size_t col = cbase + n * 16;
                outp[row * CO + col] = f2b(acc[m][n][r]);
            }
#undef LOADA
#undef WRITEA
#undef LOADB
}

// ---------------------------------------------------------------------------
// Deformable sampling + attention v3 (R8-proven): phase-split K/V full prefetch.
__global__ __launch_bounds__(256) void k_attn(const unsigned short* __restrict__ kp,
                                              const unsigned short* __restrict__ vp,
                                              const unsigned short* __restrict__ qh,
                                              const float* __restrict__ loc,
                                              unsigned short* __restrict__ aout) {
    int t = threadIdx.x;
    int wv = t >> 6, l = t & 63;
    int blk = blockIdx.x;
    int xcd = blk & 7;
    int b = xcd >> 1;
    int idx = ((blk >> 3) << 1) | (xcd & 1);
    int bq = (b << 12) | (idx << 2) | wv;

    float qv[4];
    {
        uint2 qr = *reinterpret_cast<const uint2*>(qh + (size_t)bq * CO + l * 4);
        b2f2(qr.x, qv[0], qv[1]);
        b2f2(qr.y, qv[2], qv[3]);
    }
    const unsigned short* kb = kp + (size_t)b * NPIX * CO + l * 4;
    const unsigned short* vb = vp + (size_t)b * NPIX * CO + l * 4;
    const float* lq = loc + (size_t)bq * (NS * 2);

    int i00[NS];
    float w00[NS], w01[NS], w10[NS], w11[NS];
    unsigned msks = 0;
#pragma unroll
    for (int s = 0; s < NS; ++s) {
        float gx = (lq[2 * s] + 1.f) * (WFEAT * 0.5f) - 0.5f;
        float gy = (lq[2 * s + 1] + 1.f) * (HFEAT * 0.5f) - 0.5f;
        float x0f = floorf(gx), y0f = floorf(gy);
        int x0 = (int)x0f, y0 = (int)y0f;
        float wx1 = gx - x0f, wy1 = gy - y0f;
        float wx0 = 1.f - wx1, wy0 = 1.f - wy1;
        w00[s] = wx0 * wy0; w01[s] = wx1 * wy0;
        w10[s] = wx0 * wy1; w11[s] = wx1 * wy1;
        unsigned xa = (unsigned)x0 < WFEAT, xb = (unsigned)(x0 + 1) < WFEAT;
        unsigned ya = (unsigned)y0 < HFEAT, yb = (unsigned)(y0 + 1) < HFEAT;
        msks |= ((xa & ya) | ((xb & ya) << 1) | ((xa & yb) << 2) | ((xb & yb) << 3)) << (4 * s);
        i00[s] = (y0 * WFEAT + x0) * CO;
    }

    uint2 cr[NS][4];
#pragma unroll
    for (int s = 0; s < NS; ++s) {
        uint2 z = make_uint2(0u, 0u);
        cr[s][0] = z; cr[s][1] = z; cr[s][2] = z; cr[s][3] = z;
        unsigned m4 = msks >> (4 * s);
        if (m4 & 1) cr[s][0] = *(const uint2*)(kb + i00[s]);
        if (m4 & 2) cr[s][1] = *(const uint2*)(kb + i00[s] + CO);
        if (m4 & 4) cr[s][2] = *(const uint2*)(kb + i00[s] + WFEAT * CO);
        if (m4 & 8) cr[s][3] = *(const uint2*)(kb + i00[s] + (WFEAT + 1) * CO);
    }
    float lg[NS];
#pragma unroll
    for (int s = 0; s < NS; ++s) {
        float d[4];
#pragma unroll
        for (int c = 0; c < 4; ++c) {
            float a0, a1, a2, a3;
            b2f2(cr[s][c].x, a0, a1);
            b2f2(cr[s][c].y, a2, a3);
            d[c] = fmaf(qv[0], a0, fmaf(qv[1], a1, fmaf(qv[2], a2, qv[3] * a3)));
        }
        float p = fmaf(d[0], w00[s], fmaf(d[1], w01[s], fmaf(d[2], w10[s], d[3] * w11[s])));
        p += __shfl_xor(p, 1);
        p += __shfl_xor(p, 2);
        p += __shfl_xor(p, 4);
        lg[s] = p * 0.0625f;  // 1/sqrt(256)
    }
    float mx = fmaxf(fmaxf(fmaxf(lg[0], lg[1]), fmaxf(lg[2], lg[3])),
                     fmaxf(fmaxf(lg[4], lg[5]), fmaxf(lg[6], lg[7])));
    float ws[NS];
    float sum = 0.f;
#pragma unroll
    for (int s = 0; s < NS; ++s) { ws[s] = __expf(lg[s] - mx); sum += ws[s]; }
    float inv = 1.f / sum;
#pragma unroll
    for (int s = 0; s < NS; ++s) ws[s] *= inv;

#pragma unroll
    for (int s = 0; s < NS; ++s) {
        uint2 z = make_uint2(0u, 0u);
        cr[s][0] = z; cr[s][1] = z; cr[s][2] = z; cr[s][3] = z;
        unsigned m4 = msks >> (4 * s);
        if (m4 & 1) cr[s][0] = *(const uint2*)(vb + i00[s]);
        if (m4 & 2) cr[s][1] = *(const uint2*)(vb + i00[s] + CO);
        if (m4 & 4) cr[s][2] = *(const uint2*)(vb + i00[s] + WFEAT * CO);
        if (m4 & 8) cr[s][3] = *(const uint2*)(vb + i00[s] + (WFEAT + 1) * CO);
    }
    float o0 = 0.f, o1 = 0.f, o2 = 0.f, o3 = 0.f;
#pragma unroll
    for (int s = 0; s < NS; ++s) {
        float f0 = ws[s] * w00[s], f1 = ws[s] * w01[s];
        float f2 = ws[s] * w10[s], f3 = ws[s] * w11[s];
        float a0, a1, a2, a3;
        b2f2(cr[s][0].x, a0, a1); b2f2(cr[s][0].y, a2, a3);
        o0 = fmaf(f0, a0, o0); o1 = fmaf(f0, a1, o1);
        o2 = fmaf(f0, a2, o2); o3 = fmaf(f0, a3, o3);
        b2f2(cr[s][1].x, a0, a1); b2f2(cr[s][1].y, a2, a3);
        o0 = fmaf(f1, a0, o0); o1 = fmaf(f1, a1, o1);
        o2 = fmaf(f1, a2, o2); o3 = fmaf(f1, a3, o3);
        b2f2(cr[s][2].x, a0, a1); b2f2(cr[s][2].y, a2, a3);
        o0 = fmaf(f2, a0, o0); o1 = fmaf(f2, a1, o1);
        o2 = fmaf(f2, a2, o2); o3 = fmaf(f2, a3, o3);
        b2f2(cr[s][3].x, a0, a1); b2f2(cr[s][3].y, a2, a3);
        o0 = fmaf(f3, a0, o0); o1 = fmaf(f3, a1, o1);
        o2 = fmaf(f3, a2, o2); o3 = fmaf(f3, a3, o3);
    }

    uint2 pk;
    pk.x = cvtpk(o0, o1);
    pk.y = cvtpk(o2, o3);
    *reinterpret_cast<uint2*>(aout + (size_t)bq * CO + l * 4) = pk;
}

// ---------------------------------------------------------------------------
extern "C" void kernel_launch(void* const* d_in, const int* in_sizes, int n_in,
                              void* d_out, int out_size, void* d_ws, size_t ws_size,
                              hipStream_t stream) {
    (void)in_sizes; (void)n_in; (void)out_size; (void)ws_size;
    const float* queries = (const float*)d_in[0];
    const float* keys    = (const float*)d_in[1];
    const float* values  = (const float*)d_in[2];
    const float* W_loc   = (const float*)d_in[3];
    const float* b_loc   = (const float*)d_in[4];
    const float* W_q     = (const float*)d_in[5];
    const float* b_q     = (const float*)d_in[6];
    const float* W_k     = (const float*)d_in[7];
    const float* b_k     = (const float*)d_in[8];
    const float* W_v     = (const float*)d_in[9];
    const float* b_v     = (const float*)d_in[10];
    const float* W_o     = (const float*)d_in[11];
    const float* b_o     = (const float*)d_in[12];
    float* out = (float*)d_out;

    char* ws = (char*)d_ws;
    unsigned short* kp   = (unsigned short*)(ws);                  // 32 MB
    unsigned short* vp   = (unsigned short*)(ws + 33554432);       // 32 MB
    unsigned short* qbf  = (unsigned short*)(ws + 67108864);       // 8 MB
    unsigned short* aout = (unsigned short*)(ws + 67108864);       // reuses qbf (dead by k_attn)
    unsigned short* qh   = (unsigned short*)(ws + 75497472);       // 8 MB
    float* locb          = (float*)(ws + 83886080);                // 1 MB
    unsigned short* wbuf = (unsigned short*)(ws + 84934656);       // 512 KB

    k_prep_w<<<dim3(64, 4), 256, 0, stream>>>(W_k, W_v, W_q, W_o, wbuf);
    k_qprep<<<dim3(512), 256, 0, stream>>>(queries, W_loc, b_loc, locb, qbf);
    k_gemm<1><<<dim3(256), 256, 0, stream>>>(qbf, wbuf + 131072, b_q, qh);
    k_proj<<<dim3(2048), 256, 0, stream>>>(keys, values, wbuf, b_k, b_v, kp, vp);
    k_attn<<<dim3(NB * NQ / 4), 256, 0, stream>>>(kp, vp, qh, locb, aout);
    k_gemm<0><<<dim3(256), 256, 0, stream>>>(aout, wbuf + 196608, b_o, out);
}